// Round 9
// baseline (95.978 us; speedup 1.0000x reference)
//
#include <hip/hip_runtime.h>
#include <math.h>

#define NB 32
#define NS 4096
#define ND 160
#define ND4 40              // ND in float4
#define NM 16
#define NR 16
#define TPB 64              // tokens per block
#define NCB (NS / TPB)      // 64 chunks per batch
#define BT 128              // threads per block (2 waves)

// ---------------------------------------------------------------------------
// Kernel 1: read path with in-kernel K/V fold (R8 proved a separate fold
// kernel costs ~8us of launch overhead; in-kernel it overlaps and is free).
//   K[m][d] = 0.25 * sum_r mem16[m][r] * Wrk[r][d]
//   V[m][d] =        sum_r mem16[m][r] * Wrv[d][r]
//   scores = q·K^T, softmax, out = attn·V
// Geometry: 8 lanes per group, 4 TOKENS per group (halves LDS-pipe traffic
// per token vs ntok=2 -> ~13us/CU serialized, under the ~27us HBM floor).
// block=128 (2 waves), grid=(64,32)=2048 blocks -> 8 blocks/CU submitted.
// NO VGPR cap (R4/R6: caps => spills => 2-5x HBM amplification); natural
// footprint ~110-120 (sc[4][16]=64 + transients), R5 compiled this spill-free.
// Fused: partial column-sums of `interface` -> ipart.
// ---------------------------------------------------------------------------
__global__ __launch_bounds__(BT) void ulm_read_kernel(
    const float* __restrict__ query,
    const float* __restrict__ iface,
    const float* __restrict__ memory,
    const float* __restrict__ Wrk,     // [NR][ND]
    const float* __restrict__ Wrv,     // [ND][NR]
    float* __restrict__ read_out,      // [NB][NS][ND]
    float* __restrict__ ipart)         // [NB][NCB][ND]
{
    __shared__ __align__(16) float sKV[2 * NM * ND];  // 20 KB: K then V
    __shared__ float sM16[NM * NR];                   // 1 KB
    __shared__ float4 sIred[2 * ND4];                 // 1.25 KB

    const int t = threadIdx.x;
    const int chunk = blockIdx.x;
    const int b = blockIdx.y;
    const int s0 = chunk * TPB;

    // --- stage memory[b][:][:16]: 256 elements, 128 threads -----------------
    sM16[t]       = memory[((size_t)b * NM + (t >> 4)) * ND + (t & 15)];
    sM16[t + 128] = memory[((size_t)b * NM + 8 + (t >> 4)) * ND + (t & 15)];
    __syncthreads();

    // --- fold weights into LDS K,V; threads cover d = t and d = t+128 ------
    for (int d = t; d < ND; d += BT) {
        float wk[NR], wv[NR];
#pragma unroll
        for (int r = 0; r < NR; ++r) wk[r] = Wrk[r * ND + d];
        const float4* wrv4 = reinterpret_cast<const float4*>(Wrv + d * NR);
#pragma unroll
        for (int j = 0; j < 4; ++j) {
            float4 v = wrv4[j];
            wv[j * 4 + 0] = v.x; wv[j * 4 + 1] = v.y;
            wv[j * 4 + 2] = v.z; wv[j * 4 + 3] = v.w;
        }
#pragma unroll
        for (int m = 0; m < NM; ++m) {
            float aK = 0.f, aV = 0.f;
#pragma unroll
            for (int r = 0; r < NR; ++r) {
                float mv = sM16[m * NR + r];
                aK += mv * wk[r];
                aV += mv * wv[r];
            }
            sKV[m * ND + d]           = aK * 0.25f;   // fold 1/sqrt(R)
            sKV[NM * ND + m * ND + d] = aV;
        }
    }
    __syncthreads();

    const float4* sK4 = reinterpret_cast<const float4*>(sKV);
    const float4* sV4 = sK4 + NM * ND4;

    const int l = t & 7;                  // lane in 8-lane group
    const int G = t >> 3;                 // group 0..15
    const int tokb = G * 4;               // 4 tokens per group

    const float4* q4 = reinterpret_cast<const float4*>(query + ((size_t)b * NS + s0) * ND);

    // --- scores: 16 dots of length 160 per token, 8-lane distributed -------
    float sc[4][NM];
#pragma unroll
    for (int i = 0; i < 4; ++i)
#pragma unroll
        for (int m = 0; m < NM; ++m) sc[i][m] = 0.f;

#pragma unroll
    for (int k = 0; k < 5; ++k) {
        float4 qa[4];
#pragma unroll
        for (int i = 0; i < 4; ++i) qa[i] = q4[(tokb + i) * ND4 + l + 8 * k];
#pragma unroll
        for (int m = 0; m < NM; ++m) {
            float4 kv = sK4[m * ND4 + l + 8 * k];
#pragma unroll
            for (int i = 0; i < 4; ++i)
                sc[i][m] += qa[i].x * kv.x + qa[i].y * kv.y
                          + qa[i].z * kv.z + qa[i].w * kv.w;
        }
    }
#pragma unroll
    for (int i = 0; i < 4; ++i)
#pragma unroll
        for (int m = 0; m < NM; ++m) {
            float v = sc[i][m];
            v += __shfl_xor(v, 1);
            v += __shfl_xor(v, 2);
            v += __shfl_xor(v, 4);
            sc[i][m] = v;
        }

    // --- softmax (redundant per lane; 16-wide) -----------------------------
#pragma unroll
    for (int i = 0; i < 4; ++i) {
        float mx = -1e30f;
#pragma unroll
        for (int m = 0; m < NM; ++m) mx = fmaxf(mx, sc[i][m]);
        float sm = 0.f;
#pragma unroll
        for (int m = 0; m < NM; ++m) { float e = __expf(sc[i][m] - mx); sc[i][m] = e; sm += e; }
        float inv = 1.f / sm;
#pragma unroll
        for (int m = 0; m < NM; ++m) sc[i][m] *= inv;
    }

    // --- iface partial sums: per-k load + immediate butterfly --------------
    const float4* i4 = reinterpret_cast<const float4*>(iface + ((size_t)b * NS + s0) * ND);
    const int w = t >> 6;                 // wave id in block (0/1)
#pragma unroll
    for (int k = 0; k < 5; ++k) {
        float x = 0.f, y = 0.f, z = 0.f, u = 0.f;
#pragma unroll
        for (int i = 0; i < 4; ++i) {
            float4 v = i4[(tokb + i) * ND4 + l + 8 * k];
            x += v.x; y += v.y; z += v.z; u += v.w;
        }
#pragma unroll
        for (int off = 8; off <= 32; off <<= 1) {
            x += __shfl_xor(x, off); y += __shfl_xor(y, off);
            z += __shfl_xor(z, off); u += __shfl_xor(u, off);
        }
        if ((t & 63) < 8) sIred[w * ND4 + k * 8 + l] = make_float4(x, y, z, u);
    }

    // --- out = attn · V ------------------------------------------------------
    float4* out4 = reinterpret_cast<float4*>(read_out + ((size_t)b * NS + s0) * ND);
#pragma unroll
    for (int k = 0; k < 5; ++k) {
        float4 o[4];
#pragma unroll
        for (int i = 0; i < 4; ++i) o[i] = make_float4(0.f, 0.f, 0.f, 0.f);
#pragma unroll
        for (int m = 0; m < NM; ++m) {
            float4 vv = sV4[m * ND4 + l + 8 * k];
#pragma unroll
            for (int i = 0; i < 4; ++i) {
                o[i].x += sc[i][m] * vv.x; o[i].y += sc[i][m] * vv.y;
                o[i].z += sc[i][m] * vv.z; o[i].w += sc[i][m] * vv.w;
            }
        }
#pragma unroll
        for (int i = 0; i < 4; ++i)
            out4[(tokb + i) * ND4 + l + 8 * k] = o[i];
    }

    // --- finish interface reduction: 2 wave-partials -> 1, store to ws -----
    __syncthreads();
    if (t < ND4) {
        float4 a0 = sIred[t], a1 = sIred[ND4 + t];
        float4 tot = make_float4(a0.x + a1.x, a0.y + a1.y,
                                 a0.z + a1.z, a0.w + a1.w);
        reinterpret_cast<float4*>(ipart + ((size_t)(b * NCB + chunk)) * ND)[t] = tot;
    }
}

// ---------------------------------------------------------------------------
// Kernel 2: write path. i_mean -> i_proj -> erase/add -> layer_norm(new_mem)
// grid = NB, block = 256
// ---------------------------------------------------------------------------
__global__ __launch_bounds__(256) void ulm_write_kernel(
    const float* __restrict__ memory,
    const float* __restrict__ Wwk,     // [NR][ND]
    const float* __restrict__ Wwe,     // [ND][NR]
    const float* __restrict__ Wwa,     // [ND][NR]
    const float* __restrict__ ipart,   // [NB][NCB][ND]
    float* __restrict__ new_mem)       // [NB][NM][ND]
{
    __shared__ float sIm[ND];
    __shared__ float sIp[NR];
    __shared__ float sOmE[ND];   // 1 - erase
    __shared__ float sAdd[ND];

    const int b = blockIdx.x;
    const int t = threadIdx.x;

    if (t < ND) {
        float acc = 0.f;
#pragma unroll 8
        for (int c = 0; c < NCB; ++c)
            acc += ipart[((size_t)(b * NCB + c)) * ND + t];
        sIm[t] = acc * (1.0f / NS);
    }
    __syncthreads();

    if (t < NR) {
        float acc = 0.f;
        for (int d = 0; d < ND; ++d) acc += sIm[d] * Wwk[t * ND + d];
        sIp[t] = acc;
    }
    __syncthreads();

    if (t < ND) {
        float e = 0.f, a = 0.f;
#pragma unroll
        for (int r = 0; r < NR; ++r) {
            float ip = sIp[r];
            e += ip * Wwe[t * NR + r];
            a += ip * Wwa[t * NR + r];
        }
        sOmE[t] = 1.0f - 1.0f / (1.0f + __expf(-e));
        sAdd[t] = a;
    }
    __syncthreads();

    // layer norm each of the 16 memory rows; one wave per row
    const int wave = t >> 6, lane = t & 63;
    for (int m = wave; m < NM; m += 4) {
        const float* mrow = memory + ((size_t)b * NM + m) * ND;
        float v0 = mrow[lane] * sOmE[lane] + sAdd[lane];
        float v1 = mrow[lane + 64] * sOmE[lane + 64] + sAdd[lane + 64];
        float v2 = 0.f;
        const bool has2 = lane < 32;
        if (has2) v2 = mrow[lane + 128] * sOmE[lane + 128] + sAdd[lane + 128];
        float s  = v0 + v1 + v2;
        float sq = v0 * v0 + v1 * v1 + v2 * v2;
#pragma unroll
        for (int off = 32; off; off >>= 1) {
            s  += __shfl_xor(s, off);
            sq += __shfl_xor(sq, off);
        }
        float mu   = s * (1.0f / ND);
        float var  = sq * (1.0f / ND) - mu * mu;
        float rstd = rsqrtf(var + 1e-5f);
        float* orow = new_mem + ((size_t)b * NM + m) * ND;
        orow[lane]      = (v0 - mu) * rstd;
        orow[lane + 64] = (v1 - mu) * rstd;
        if (has2) orow[lane + 128] = (v2 - mu) * rstd;
    }
}

extern "C" void kernel_launch(void* const* d_in, const int* in_sizes, int n_in,
                              void* d_out, int out_size, void* d_ws, size_t ws_size,
                              hipStream_t stream) {
    const float* query  = (const float*)d_in[0];
    const float* iface  = (const float*)d_in[1];
    const float* memory = (const float*)d_in[2];
    const float* Wrk    = (const float*)d_in[3];
    const float* Wrv    = (const float*)d_in[4];
    const float* Wwk    = (const float*)d_in[5];
    const float* Wwe    = (const float*)d_in[6];
    const float* Wwa    = (const float*)d_in[7];

    float* read_out = (float*)d_out;                        // [32][4096][160]
    float* new_mem  = (float*)d_out + (size_t)NB * NS * ND; // [32][16][160]
    float* ipart    = (float*)d_ws;                         // NB*NCB*ND f32 = 1.31 MB

    dim3 grid1(NCB, NB);
    ulm_read_kernel<<<grid1, BT, 0, stream>>>(query, iface, memory, Wrk, Wrv,
                                              read_out, ipart);
    ulm_write_kernel<<<NB, 256, 0, stream>>>(memory, Wwk, Wwe, Wwa, ipart, new_mem);
}

// Round 10
// 56.125 us; speedup vs baseline: 1.7101x; 1.7101x over previous
//
#include <hip/hip_runtime.h>
#include <hip/hip_bf16.h>
#include <math.h>

#define NB 32
#define NS 4096
#define ND 160
#define ND4 40              // ND in float4
#define NM 16
#define NR 16
#define TPB 256             // tokens per block (64 per wave)
#define NCB (NS / TPB)      // 16 chunks per batch

typedef float  f32x4  __attribute__((ext_vector_type(4)));
typedef short  bf16x8 __attribute__((ext_vector_type(8)));
typedef unsigned int u32x4 __attribute__((ext_vector_type(4)));

// RNE f32 -> bf16, packed pair (lo in low 16, hi in high 16)
__device__ __forceinline__ unsigned bfpair(float lo, float hi) {
    union { float f; unsigned u; } a, c;
    a.f = lo; c.f = hi;
    unsigned ua = (a.u + 0x7FFFu + ((a.u >> 16) & 1u)) >> 16;
    unsigned uc = (c.u + 0x7FFFu + ((c.u >> 16) & 1u)) >> 16;
    return (uc << 16) | (ua & 0xFFFFu);
}

__device__ __forceinline__ bf16x8 mkfrag(unsigned w0, unsigned w1,
                                         unsigned w2, unsigned w3) {
    union { u32x4 u; bf16x8 h; } x;
    x.u = (u32x4){w0, w1, w2, w3};
    return x.h;
}

// ---------------------------------------------------------------------------
// Kernel 1: MFMA read path.
//  Fold (f32, in LDS):  K'[m][d] = 0.25*sum_r mem16[m][r]*Wrk[r][d]
//                       V [m][d] =      sum_r mem16[m][r]*Wrv[d][r]
//  Per wave (64 tokens, 4 sets of 16):
//    S^T  = mfma(A=K'(16x160), B=Q^T)          // D[m][tok], 5 mfma/set
//    softmax in-register (2 shfl_xor)
//    P^T via 640B wave-private LDS regroup
//    C^T  = mfma(A=V^T(160x16 pad32), B=P^T)   // D2[d][tok], 10 mfma/set
//  DS+VALU collapse ~10x vs dot-product version -> memory-bound.
//  NO VGPR cap (R4/R6/R9: caps or fat scopes => spills => HBM amplification).
// grid = (NCB=16, NB=32) = 512 blocks, 256 threads.
// ---------------------------------------------------------------------------
__global__ __launch_bounds__(256) void ulm_read_kernel(
    const float* __restrict__ query,
    const float* __restrict__ iface,
    const float* __restrict__ memory,
    const float* __restrict__ Wrk,     // [NR][ND]
    const float* __restrict__ Wrv,     // [ND][NR]
    float* __restrict__ read_out,      // [NB][NS][ND]
    float* __restrict__ ipart)         // [NB][NCB][ND]
{
    __shared__ __align__(16) float sKV[2 * NM * ND];  // 20 KB: K' then V (f32)
    __shared__ float sM16[NM * NR];                   // 1 KB
    __shared__ unsigned sP[4][16 * 10];               // P^T bf16 pairs, per wave
    __shared__ float4 sIred[4 * ND4];                 // 2.5 KB

    const int t = threadIdx.x;
    const int chunk = blockIdx.x;
    const int b = blockIdx.y;
    const int s0 = chunk * TPB;
    const int w  = t >> 6;             // wave 0..3
    const int l  = t & 63;
    const int lr = l & 15;             // MFMA row/col lane id
    const int lg = l >> 4;             // k-group 0..3

    // --- stage memory[b][:][:16] --------------------------------------------
    sM16[t] = memory[((size_t)b * NM + (t >> 4)) * ND + (t & 15)];
    __syncthreads();

    // --- fold K',V into LDS (f32), threads t<160, one d-column each ---------
    if (t < ND) {
        float wk[NR], wv[NR];
#pragma unroll
        for (int r = 0; r < NR; ++r) wk[r] = Wrk[r * ND + t];
        const float4* wrv4 = reinterpret_cast<const float4*>(Wrv + t * NR);
#pragma unroll
        for (int j = 0; j < 4; ++j) {
            float4 v = wrv4[j];
            wv[j * 4 + 0] = v.x; wv[j * 4 + 1] = v.y;
            wv[j * 4 + 2] = v.z; wv[j * 4 + 3] = v.w;
        }
#pragma unroll
        for (int m = 0; m < NM; ++m) {
            float aK = 0.f, aV = 0.f;
#pragma unroll
            for (int r = 0; r < NR; ++r) {
                float mv = sM16[m * NR + r];
                aK += mv * wk[r];
                aV += mv * wv[r];
            }
            sKV[m * ND + t]           = aK * 0.25f;   // fold 1/sqrt(R)
            sKV[NM * ND + m * ND + t] = aV;
        }
    }
    __syncthreads();

    // --- K' A-frags: lane holds K'[row=lr][k = lg*8+j + 32*kb], 5 kb --------
    bf16x8 kf[5];
#pragma unroll
    for (int kb = 0; kb < 5; ++kb) {
        const float* src = &sKV[lr * ND + lg * 8 + kb * 32];
        float4 a = *reinterpret_cast<const float4*>(src);
        float4 c = *reinterpret_cast<const float4*>(src + 4);
        kf[kb] = mkfrag(bfpair(a.x, a.y), bfpair(a.z, a.w),
                        bfpair(c.x, c.y), bfpair(c.z, c.w));
    }

    // --- V^T A-frags (K=m padded to 32): lane holds V[m=lg*8+j][dblk*16+lr] -
    // groups lg>=2 are the zero-pad (m>=16) -> zero frags.
    bf16x8 vf[10];
#pragma unroll
    for (int d = 0; d < 10; ++d) {
        if (lg < 2) {
            float f0 = sKV[NM*ND + (lg*8 + 0) * ND + d*16 + lr];
            float f1 = sKV[NM*ND + (lg*8 + 1) * ND + d*16 + lr];
            float f2 = sKV[NM*ND + (lg*8 + 2) * ND + d*16 + lr];
            float f3 = sKV[NM*ND + (lg*8 + 3) * ND + d*16 + lr];
            float f4 = sKV[NM*ND + (lg*8 + 4) * ND + d*16 + lr];
            float f5 = sKV[NM*ND + (lg*8 + 5) * ND + d*16 + lr];
            float f6 = sKV[NM*ND + (lg*8 + 6) * ND + d*16 + lr];
            float f7 = sKV[NM*ND + (lg*8 + 7) * ND + d*16 + lr];
            vf[d] = mkfrag(bfpair(f0, f1), bfpair(f2, f3),
                           bfpair(f4, f5), bfpair(f6, f7));
        } else {
            vf[d] = mkfrag(0u, 0u, 0u, 0u);
        }
    }

    const size_t base = (size_t)b * NS * ND;
    const float4* q4  = reinterpret_cast<const float4*>(query + base) + (size_t)s0 * ND4;
    float4* out4      = reinterpret_cast<float4*>(read_out + base) + (size_t)s0 * ND4;
    const int wtok0 = w * 64;          // wave's token base within block
    unsigned* pl = &sP[w][0];

#pragma unroll 1
    for (int set = 0; set < 4; ++set) {
        const int tok = wtok0 + set * 16 + lr;

        // Q^T B-frags: lane holds Q[tok=lr][d = lg*8+j + 32*kb] (f32->bf16)
        float4 qr[10];
#pragma unroll
        for (int kb = 0; kb < 5; ++kb) {
            qr[2*kb]   = q4[(size_t)tok * ND4 + lg * 2 + kb * 8];
            qr[2*kb+1] = q4[(size_t)tok * ND4 + lg * 2 + kb * 8 + 1];
        }

        // scores^T: D[m = lg*4+r][tok = lr]
        f32x4 D = {0.f, 0.f, 0.f, 0.f};
#pragma unroll
        for (int kb = 0; kb < 5; ++kb) {
            bf16x8 qf = mkfrag(bfpair(qr[2*kb].x,   qr[2*kb].y),
                               bfpair(qr[2*kb].z,   qr[2*kb].w),
                               bfpair(qr[2*kb+1].x, qr[2*kb+1].y),
                               bfpair(qr[2*kb+1].z, qr[2*kb+1].w));
            D = __builtin_amdgcn_mfma_f32_16x16x32_bf16(kf[kb], qf, D, 0, 0, 0);
        }

        // softmax over m (rows): in-lane 4 + cross-group xor16, xor32
        float mx = fmaxf(fmaxf(D[0], D[1]), fmaxf(D[2], D[3]));
        mx = fmaxf(mx, __shfl_xor(mx, 16));
        mx = fmaxf(mx, __shfl_xor(mx, 32));
        float e0 = __expf(D[0] - mx), e1 = __expf(D[1] - mx);
        float e2 = __expf(D[2] - mx), e3 = __expf(D[3] - mx);
        float sm = e0 + e1 + e2 + e3;
        sm += __shfl_xor(sm, 16);
        sm += __shfl_xor(sm, 32);
        float inv = 1.f / sm;
        e0 *= inv; e1 *= inv; e2 *= inv; e3 *= inv;

        // P^T regroup via wave-private LDS: row tok=lr, word mp = m/2
        pl[lr * 10 + lg * 2 + 0] = bfpair(e0, e1);
        pl[lr * 10 + lg * 2 + 1] = bfpair(e2, e3);
        asm volatile("s_waitcnt lgkmcnt(0)" ::: "memory");
        // B-frag: lane needs P^T[m = lg*8+j][tok=lr]; lg>=2 is pad (A side 0)
        int pb = (lg < 2) ? (lr * 10 + lg * 4) : 0;
        bf16x8 pf = mkfrag(pl[pb], pl[pb + 1], pl[pb + 2], pl[pb + 3]);

        // content^T: D2[d = dblk*16 + lg*4 + r][tok=lr]; regs r consecutive d
#pragma unroll
        for (int d = 0; d < 10; ++d) {
            f32x4 D2 = {0.f, 0.f, 0.f, 0.f};
            D2 = __builtin_amdgcn_mfma_f32_16x16x32_bf16(vf[d], pf, D2, 0, 0, 0);
            out4[(size_t)tok * ND4 + d * 4 + lg] =
                make_float4(D2[0], D2[1], D2[2], D2[3]);
        }
    }

    // --- iface column-sums for this wave's 64 tokens ------------------------
    const float4* i4 = reinterpret_cast<const float4*>(iface + base) + (size_t)s0 * ND4;
    const int l8 = l & 7, g8 = l >> 3;
    float4 ia[5];
#pragma unroll
    for (int k = 0; k < 5; ++k) ia[k] = make_float4(0.f, 0.f, 0.f, 0.f);
#pragma unroll
    for (int i = 0; i < 8; ++i) {
        int tk = wtok0 + g8 * 8 + i;
#pragma unroll
        for (int k = 0; k < 5; ++k) {
            float4 v = i4[(size_t)tk * ND4 + l8 + 8 * k];
            ia[k].x += v.x; ia[k].y += v.y; ia[k].z += v.z; ia[k].w += v.w;
        }
    }
#pragma unroll
    for (int k = 0; k < 5; ++k) {
        float x = ia[k].x, y = ia[k].y, z = ia[k].z, u = ia[k].w;
#pragma unroll
        for (int off = 8; off <= 32; off <<= 1) {
            x += __shfl_xor(x, off); y += __shfl_xor(y, off);
            z += __shfl_xor(z, off); u += __shfl_xor(u, off);
        }
        if (l < 8) sIred[w * ND4 + k * 8 + l8] = make_float4(x, y, z, u);
    }
    __syncthreads();
    if (t < ND4) {
        float4 a0 = sIred[t], a1 = sIred[ND4 + t];
        float4 a2 = sIred[2 * ND4 + t], a3 = sIred[3 * ND4 + t];
        float4 tot = make_float4(a0.x + a1.x + a2.x + a3.x,
                                 a0.y + a1.y + a2.y + a3.y,
                                 a0.z + a1.z + a2.z + a3.z,
                                 a0.w + a1.w + a2.w + a3.w);
        reinterpret_cast<float4*>(ipart + ((size_t)(b * NCB + chunk)) * ND)[t] = tot;
    }
}

// ---------------------------------------------------------------------------
// Kernel 2: write path. i_mean -> i_proj -> erase/add -> layer_norm(new_mem)
// grid = NB, block = 256
// ---------------------------------------------------------------------------
__global__ __launch_bounds__(256) void ulm_write_kernel(
    const float* __restrict__ memory,
    const float* __restrict__ Wwk,     // [NR][ND]
    const float* __restrict__ Wwe,     // [ND][NR]
    const float* __restrict__ Wwa,     // [ND][NR]
    const float* __restrict__ ipart,   // [NB][NCB][ND]
    float* __restrict__ new_mem)       // [NB][NM][ND]
{
    __shared__ float sIm[ND];
    __shared__ float sIp[NR];
    __shared__ float sOmE[ND];   // 1 - erase
    __shared__ float sAdd[ND];

    const int b = blockIdx.x;
    const int t = threadIdx.x;

    if (t < ND) {
        float acc = 0.f;
#pragma unroll
        for (int c = 0; c < NCB; ++c)
            acc += ipart[((size_t)(b * NCB + c)) * ND + t];
        sIm[t] = acc * (1.0f / NS);
    }
    __syncthreads();

    if (t < NR) {
        float acc = 0.f;
        for (int d = 0; d < ND; ++d) acc += sIm[d] * Wwk[t * ND + d];
        sIp[t] = acc;
    }
    __syncthreads();

    if (t < ND) {
        float e = 0.f, a = 0.f;
#pragma unroll
        for (int r = 0; r < NR; ++r) {
            float ip = sIp[r];
            e += ip * Wwe[t * NR + r];
            a += ip * Wwa[t * NR + r];
        }
        sOmE[t] = 1.0f - 1.0f / (1.0f + __expf(-e));
        sAdd[t] = a;
    }
    __syncthreads();

    // layer norm each of the 16 memory rows; one wave per row
    const int wave = t >> 6, lane = t & 63;
    for (int m = wave; m < NM; m += 4) {
        const float* mrow = memory + ((size_t)b * NM + m) * ND;
        float v0 = mrow[lane] * sOmE[lane] + sAdd[lane];
        float v1 = mrow[lane + 64] * sOmE[lane + 64] + sAdd[lane + 64];
        float v2 = 0.f;
        const bool has2 = lane < 32;
        if (has2) v2 = mrow[lane + 128] * sOmE[lane + 128] + sAdd[lane + 128];
        float s  = v0 + v1 + v2;
        float sq = v0 * v0 + v1 * v1 + v2 * v2;
#pragma unroll
        for (int off = 32; off; off >>= 1) {
            s  += __shfl_xor(s, off);
            sq += __shfl_xor(sq, off);
        }
        float mu   = s * (1.0f / ND);
        float var  = sq * (1.0f / ND) - mu * mu;
        float rstd = rsqrtf(var + 1e-5f);
        float* orow = new_mem + ((size_t)b * NM + m) * ND;
        orow[lane]      = (v0 - mu) * rstd;
        orow[lane + 64] = (v1 - mu) * rstd;
        if (has2) orow[lane + 128] = (v2 - mu) * rstd;
    }
}

extern "C" void kernel_launch(void* const* d_in, const int* in_sizes, int n_in,
                              void* d_out, int out_size, void* d_ws, size_t ws_size,
                              hipStream_t stream) {
    const float* query  = (const float*)d_in[0];
    const float* iface  = (const float*)d_in[1];
    const float* memory = (const float*)d_in[2];
    const float* Wrk    = (const float*)d_in[3];
    const float* Wrv    = (const float*)d_in[4];
    const float* Wwk    = (const float*)d_in[5];
    const float* Wwe    = (const float*)d_in[6];
    const float* Wwa    = (const float*)d_in[7];

    float* read_out = (float*)d_out;                        // [32][4096][160]
    float* new_mem  = (float*)d_out + (size_t)NB * NS * ND; // [32][16][160]
    float* ipart    = (float*)d_ws;                         // NB*NCB*ND f32

    dim3 grid1(NCB, NB);
    ulm_read_kernel<<<grid1, 256, 0, stream>>>(query, iface, memory, Wrk, Wrv,
                                               read_out, ipart);
    ulm_write_kernel<<<NB, 256, 0, stream>>>(memory, Wwk, Wwe, Wwa, ipart, new_mem);
}